// Round 1
// baseline (19401.782 us; speedup 1.0000x reference)
//
#include <hip/hip_runtime.h>
#include <math.h>

// Problem dims
#define B_ 64
#define T_ 1000
#define D_ 512
#define V_ 5000
#define L_ 150
#define H_ 512

// ws offsets (in floats)
#define OFF_SCORES 0u            // [64][1000]            = 64000
#define OFF_PM     64000u        // [20][64] chunk max    = 1280
#define OFF_PL     65280u        // [20][64] chunk sumexp = 1280
#define OFF_PCTX   66560u        // [20][64][512]         = 655360
#define OFF_XT     721920u       // xT[k<1024][b]         = 65536
#define OFF_H      787456u       // h[b][k]               = 32768
#define OFF_HT     820224u       // hT[k][b]              = 32768
#define OFF_C      852992u       // c[b][k]               = 32768
#define OFF_GP     885760u       // gp[6][2048][64]       = 786432
#define OFF_LP     1672192u      // lp[2][5000][64]       = 640000
#define OFF_ST     2312192u      // stats[79][64][4]      = 20224
// total = 2332416 floats (~9.33 MB)

// d_out offsets (floats)
#define OUT_LOGITS 0ull
#define OUT_DECLP  48000000ull
#define OUT_PRED   48009600ull
#define OUT_ATTN   48019200ull

// ---------------------------------------------------------------------------
// K1: fused attention — scores + online-softmax ctx partials, ONE enc read.
// grid (20 chunks, 64 batch), 256 thr (4 waves, each wave owns t = t0+w+4i).
// ---------------------------------------------------------------------------
__global__ __launch_bounds__(256) void k_attn(const float* __restrict__ enc,
                                              const int* __restrict__ enc_len,
                                              float* __restrict__ ws) {
  const int c = blockIdx.x;          // 0..19 -> t0 = c*50
  const int b = blockIdx.y;          // 0..63
  const int lane = threadIdx.x & 63;
  const int w = threadIdx.x >> 6;
  const int tid = threadIdx.x;

  const float* __restrict__ hb = ws + OFF_H + b * 512;
  const float4 h0 = *(const float4*)(hb + lane * 4);
  const float4 h1 = *(const float4*)(hb + 256 + lane * 4);

  float4 a0 = make_float4(0.f, 0.f, 0.f, 0.f);
  float4 a1 = make_float4(0.f, 0.f, 0.f, 0.f);
  float m = -3e38f, l = 0.f;
  const int len = enc_len[b];
  const int t0 = c * 50;
  float* __restrict__ scores = ws + OFF_SCORES + b * 1000;

  for (int t = t0 + w; t < t0 + 50; t += 4) {   // t is wave-uniform
    const bool valid = (t < len);
    float s;
    float4 e0, e1;
    if (valid) {
      const float* __restrict__ ep = enc + ((size_t)b * 1000 + t) * 512;
      e0 = *(const float4*)(ep + lane * 4);
      e1 = *(const float4*)(ep + 256 + lane * 4);
      float p = e0.x * h0.x + e0.y * h0.y + e0.z * h0.z + e0.w * h0.w
              + e1.x * h1.x + e1.y * h1.y + e1.z * h1.z + e1.w * h1.w;
      #pragma unroll
      for (int off = 1; off < 64; off <<= 1) p += __shfl_xor(p, off);
      s = p;
    } else {
      s = -1e9f;
      e0 = make_float4(0.f, 0.f, 0.f, 0.f);
      e1 = make_float4(0.f, 0.f, 0.f, 0.f);
    }
    if (lane == 0) scores[t] = s;
    if (valid) {
      const float mn = fmaxf(m, s);
      const float sc = expf(m - mn);   // m=-3e38 first time -> 0
      const float wt = expf(s - mn);
      l = l * sc + wt;
      m = mn;
      a0.x = a0.x * sc + wt * e0.x; a0.y = a0.y * sc + wt * e0.y;
      a0.z = a0.z * sc + wt * e0.z; a0.w = a0.w * sc + wt * e0.w;
      a1.x = a1.x * sc + wt * e1.x; a1.y = a1.y * sc + wt * e1.y;
      a1.z = a1.z * sc + wt * e1.z; a1.w = a1.w * sc + wt * e1.w;
    }
  }

  // block combine (4 waves -> one chunk partial)
  __shared__ float sctx[4 * 512];
  __shared__ float sm[4], sl[4];
  sctx[w * 512 + lane * 4 + 0] = a0.x;
  sctx[w * 512 + lane * 4 + 1] = a0.y;
  sctx[w * 512 + lane * 4 + 2] = a0.z;
  sctx[w * 512 + lane * 4 + 3] = a0.w;
  sctx[w * 512 + 256 + lane * 4 + 0] = a1.x;
  sctx[w * 512 + 256 + lane * 4 + 1] = a1.y;
  sctx[w * 512 + 256 + lane * 4 + 2] = a1.z;
  sctx[w * 512 + 256 + lane * 4 + 3] = a1.w;
  if (lane == 0) { sm[w] = m; sl[w] = l; }
  __syncthreads();

  const float M = fmaxf(fmaxf(sm[0], sm[1]), fmaxf(sm[2], sm[3]));
  const float f0 = expf(sm[0] - M), f1 = expf(sm[1] - M);
  const float f2 = expf(sm[2] - M), f3 = expf(sm[3] - M);
  float* __restrict__ pctx = ws + OFF_PCTX + ((size_t)c * 64 + b) * 512;
  for (int d = tid; d < 512; d += 256) {
    pctx[d] = sctx[d] * f0 + sctx[512 + d] * f1 + sctx[1024 + d] * f2 + sctx[1536 + d] * f3;
  }
  if (tid == 0) {
    ws[OFF_PM + c * 64 + b] = M;
    ws[OFF_PL + c * 64 + b] = sl[0] * f0 + sl[1] * f1 + sl[2] * f2 + sl[3] * f3;
  }
}

// ---------------------------------------------------------------------------
// K2: (a) finalize step t-1 logits stats -> dec_lp + prediction
//     (b) combine attn partials -> ctx, assemble xT (emb | ctx), write attns.
// grid 64 (one block per b), 256 thr. Called with t=150 for final finalize.
// ---------------------------------------------------------------------------
__global__ __launch_bounds__(256) void k_comb(const float* __restrict__ emb_table,
                                              const int* __restrict__ dec_in,
                                              const int* __restrict__ dec_out,
                                              float* __restrict__ ws,
                                              float* __restrict__ out, int t) {
  const int b = blockIdx.x;
  const int tid = threadIdx.x;
  __shared__ float fm[79], fl[79], fv[79];
  __shared__ int   fi[79];
  __shared__ float ef[20], spm[20], spl[20];
  __shared__ float sMS[2];

  if (t > 0) {
    const int tp = t - 1;
    if (tid < 79) {
      const float4 st = *(const float4*)(ws + OFF_ST + ((size_t)tid * 64 + b) * 4);
      fm[tid] = st.x; fl[tid] = st.y; fv[tid] = st.z; fi[tid] = (int)st.w;
    }
    __syncthreads();
    if (tid == 0) {
      float M = -3e38f;
      for (int c2 = 0; c2 < 79; ++c2) M = fmaxf(M, fm[c2]);
      float S = 0.f, bv = -3e38f;
      int bi = 0;
      for (int c2 = 0; c2 < 79; ++c2) {
        S += fl[c2] * expf(fm[c2] - M);
        if (fv[c2] > bv) { bv = fv[c2]; bi = fi[c2]; }   // ascending c2 -> first max
      }
      const float lse = logf(S) + M;
      const int tok = dec_out[b * 150 + tp];
      const float lg = out[OUT_LOGITS + ((size_t)b * 150 + tp) * 5000 + tok];
      out[OUT_DECLP + (size_t)b * 150 + tp] = lg - lse;
      out[OUT_PRED  + (size_t)b * 150 + tp] = (float)bi;
    }
    __syncthreads();
  }
  if (t >= 150) return;

  // ---- attention combine ----
  if (tid < 20) {
    spm[tid] = ws[OFF_PM + tid * 64 + b];
    spl[tid] = ws[OFF_PL + tid * 64 + b];
  }
  __syncthreads();
  if (tid == 0) {
    float M = -3e38f;
    for (int c = 0; c < 20; ++c) M = fmaxf(M, spm[c]);
    float S = 0.f;
    for (int c = 0; c < 20; ++c) {
      const float e = expf(spm[c] - M);
      ef[c] = e;
      S += spl[c] * e;
    }
    sMS[0] = M; sMS[1] = S;
  }
  __syncthreads();
  const float M = sMS[0];
  const float invS = 1.f / sMS[1];

  // ctx -> xT[512+d][b]
  for (int d = tid; d < 512; d += 256) {
    float acc = 0.f;
    #pragma unroll
    for (int c = 0; c < 20; ++c)
      acc += ws[OFF_PCTX + ((size_t)c * 64 + b) * 512 + d] * ef[c];
    ws[OFF_XT + (size_t)(512 + d) * 64 + b] = acc * invS;
  }
  // embedding -> xT[k][b]  (padding_idx = 0 -> zeros)
  const int tok = dec_in[b * 150 + t];
  const float* __restrict__ er = emb_table + (size_t)tok * 512;
  for (int k = tid; k < 512; k += 256)
    ws[OFF_XT + (size_t)k * 64 + b] = (tok != 0) ? er[k] : 0.f;
  // attn weights -> d_out
  float* __restrict__ ao = out + OUT_ATTN + ((size_t)b * 150 + t) * 1000;
  const float* __restrict__ sc = ws + OFF_SCORES + b * 1000;
  for (int tt = tid; tt < 1000; tt += 256)
    ao[tt] = expf(sc[tt] - M) * invS;   // masked scores = -1e9 -> exactly 0
}

// ---------------------------------------------------------------------------
// K3: gates partial GEMM. lane = b. Wave job: 8 rows x 64 b x 256 k.
// 1536 jobs = 256 rowgroups x 6 kchunks (4 over x[1024], 2 over h[512]).
// grid 384, 256 thr.
// ---------------------------------------------------------------------------
__global__ __launch_bounds__(256) void k_gates(const float* __restrict__ W_ih,
                                               const float* __restrict__ W_hh,
                                               float* __restrict__ ws) {
  const int w = blockIdx.x * 4 + (threadIdx.x >> 6);  // 0..1535
  const int lane = threadIdx.x & 63;                  // = b
  const int rg = w & 255;
  const int kc = w >> 8;                              // 0..5
  const int r0 = rg * 8;

  const float* __restrict__ Wp;
  const float* __restrict__ xp;
  int ld, kofs;
  if (kc < 4) { Wp = W_ih; ld = 1024; kofs = kc * 256; xp = ws + OFF_XT + (size_t)kofs * 64; }
  else        { Wp = W_hh; ld = 512;  kofs = (kc - 4) * 256; xp = ws + OFF_HT + (size_t)kofs * 64; }

  float acc[8] = {0.f, 0.f, 0.f, 0.f, 0.f, 0.f, 0.f, 0.f};
  for (int k = 0; k < 256; k += 4) {
    const float x0 = xp[(k + 0) * 64 + lane];
    const float x1 = xp[(k + 1) * 64 + lane];
    const float x2 = xp[(k + 2) * 64 + lane];
    const float x3 = xp[(k + 3) * 64 + lane];
    #pragma unroll
    for (int r = 0; r < 8; ++r) {
      const float4 wv = *(const float4*)(Wp + (size_t)(r0 + r) * ld + kofs + k);
      acc[r] += wv.x * x0 + wv.y * x1 + wv.z * x2 + wv.w * x3;
    }
  }
  float* __restrict__ gp = ws + OFF_GP + ((size_t)kc * 2048 + r0) * 64;
  #pragma unroll
  for (int r = 0; r < 8; ++r) gp[r * 64 + lane] = acc[r];
}

// ---------------------------------------------------------------------------
// K4: combine gate partials + LSTM cell. grid 128, 256 thr. lanes span b.
// ---------------------------------------------------------------------------
__global__ __launch_bounds__(256) void k_cell(const float* __restrict__ b_ih,
                                              const float* __restrict__ b_hh,
                                              float* __restrict__ ws) {
  const int g = blockIdx.x * 256 + threadIdx.x;  // 0..32767
  const int b = g & 63;
  const int hi = g >> 6;                          // 0..511
  float ai = b_ih[hi]        + b_hh[hi];
  float af = b_ih[hi + 512]  + b_hh[hi + 512];
  float ag = b_ih[hi + 1024] + b_hh[hi + 1024];
  float ao = b_ih[hi + 1536] + b_hh[hi + 1536];
  #pragma unroll
  for (int kc = 0; kc < 6; ++kc) {
    const float* __restrict__ gp = ws + OFF_GP + (size_t)kc * 2048 * 64;
    ai += gp[(hi       ) * 64 + b];
    af += gp[(hi +  512) * 64 + b];
    ag += gp[(hi + 1024) * 64 + b];
    ao += gp[(hi + 1536) * 64 + b];
  }
  const float cp = ws[OFF_C + b * 512 + hi];
  const float ig = 1.f / (1.f + expf(-ai));
  const float fg = 1.f / (1.f + expf(-af));
  const float gg = tanhf(ag);
  const float og = 1.f / (1.f + expf(-ao));
  const float c2 = fg * cp + ig * gg;
  const float h2 = og * tanhf(c2);
  ws[OFF_C + b * 512 + hi] = c2;
  ws[OFF_H + b * 512 + hi] = h2;
  ws[OFF_HT + (size_t)hi * 64 + b] = h2;
}

// ---------------------------------------------------------------------------
// K5: logits partial GEMM. lane = b. 1250 jobs = 625 vgroups x 2 ksplits.
// grid 313, 256 thr.
// ---------------------------------------------------------------------------
__global__ __launch_bounds__(256) void k_logits(const float* __restrict__ W_out,
                                                float* __restrict__ ws) {
  const int w = blockIdx.x * 4 + (threadIdx.x >> 6);
  if (w >= 1250) return;
  const int lane = threadIdx.x & 63;
  const int vg = w % 625;
  const int ks = w / 625;
  const int v0 = vg * 8;
  const int k0 = ks * 256;
  const float* __restrict__ hT = ws + OFF_HT;
  float acc[8] = {0.f, 0.f, 0.f, 0.f, 0.f, 0.f, 0.f, 0.f};
  for (int k = k0; k < k0 + 256; k += 4) {
    const float x0 = hT[(k + 0) * 64 + lane];
    const float x1 = hT[(k + 1) * 64 + lane];
    const float x2 = hT[(k + 2) * 64 + lane];
    const float x3 = hT[(k + 3) * 64 + lane];
    #pragma unroll
    for (int r = 0; r < 8; ++r) {
      const float4 wv = *(const float4*)(W_out + (size_t)(v0 + r) * 512 + k);
      acc[r] += wv.x * x0 + wv.y * x1 + wv.z * x2 + wv.w * x3;
    }
  }
  float* __restrict__ lp = ws + OFF_LP + ((size_t)ks * 5000 + v0) * 64;
  #pragma unroll
  for (int r = 0; r < 8; ++r) lp[r * 64 + lane] = acc[r];
}

// ---------------------------------------------------------------------------
// K6: combine logits ksplits + bias, write logits (coalesced via LDS
// transpose), per-(vchunk,b) online softmax stats + argmax partials.
// grid 79, 256 thr.
// ---------------------------------------------------------------------------
__global__ __launch_bounds__(256) void k_lcomb(const float* __restrict__ b_out,
                                               float* __restrict__ ws,
                                               float* __restrict__ out, int t) {
  const int vc = blockIdx.x;       // 0..78
  const int v0 = vc * 64;
  const int NV = (5000 - v0 < 64) ? (5000 - v0) : 64;
  const int tid = threadIdx.x;
  __shared__ float Ls[64 * 65];

  #pragma unroll
  for (int e = 0; e < 16; ++e) {
    const int idx = e * 256 + tid;
    const int v = idx >> 6, b = idx & 63;
    if (v < NV) {
      Ls[v * 65 + b] = ws[OFF_LP + (size_t)(v0 + v) * 64 + b]
                     + ws[OFF_LP + (size_t)(5000 + v0 + v) * 64 + b]
                     + b_out[v0 + v];
    }
  }
  __syncthreads();
  #pragma unroll
  for (int e = 0; e < 16; ++e) {
    const int idx = e * 256 + tid;
    const int v = idx & 63, b = idx >> 6;
    if (v < NV)
      out[OUT_LOGITS + ((size_t)b * 150 + t) * 5000 + v0 + v] = Ls[v * 65 + b];
  }
  if (tid < 64) {
    const int b = tid;
    float m = -3e38f, l = 0.f, bv = -3e38f;
    int bi = 0;
    for (int v = 0; v < NV; ++v) {
      const float val = Ls[v * 65 + b];
      const float mn = fmaxf(m, val);
      l = l * expf(m - mn) + expf(val - mn);
      m = mn;
      if (val > bv) { bv = val; bi = v0 + v; }   // strict > keeps first max
    }
    const float4 st = make_float4(m, l, bv, (float)bi);
    *(float4*)(ws + OFF_ST + ((size_t)vc * 64 + b) * 4) = st;
  }
}

// ---------------------------------------------------------------------------
extern "C" void kernel_launch(void* const* d_in, const int* in_sizes, int n_in,
                              void* d_out, int out_size, void* d_ws, size_t ws_size,
                              hipStream_t stream) {
  const float* enc     = (const float*)d_in[0];
  const int*   enc_len = (const int*)d_in[1];
  const int*   dec_in  = (const int*)d_in[2];
  const int*   dec_out = (const int*)d_in[3];
  const float* emb     = (const float*)d_in[4];
  const float* W_ih    = (const float*)d_in[5];
  const float* b_ih    = (const float*)d_in[6];
  const float* W_hh    = (const float*)d_in[7];
  const float* b_hh    = (const float*)d_in[8];
  const float* W_out   = (const float*)d_in[9];
  const float* b_out   = (const float*)d_in[10];
  float* out = (float*)d_out;
  float* ws  = (float*)d_ws;

  // zero h, hT, c (contiguous region)
  hipMemsetAsync(ws + OFF_H, 0, (size_t)(3 * 32768) * sizeof(float), stream);

  for (int t = 0; t < 150; ++t) {
    k_attn  <<<dim3(20, 64), 256, 0, stream>>>(enc, enc_len, ws);
    k_comb  <<<64,  256, 0, stream>>>(emb, dec_in, dec_out, ws, out, t);
    k_gates <<<384, 256, 0, stream>>>(W_ih, W_hh, ws);
    k_cell  <<<128, 256, 0, stream>>>(b_ih, b_hh, ws);
    k_logits<<<313, 256, 0, stream>>>(W_out, ws);
    k_lcomb <<<79,  256, 0, stream>>>(b_out, ws, out, t);
  }
  // finalize step 149's dec_lp / prediction
  k_comb<<<64, 256, 0, stream>>>(emb, dec_in, dec_out, ws, out, 150);
}